// Round 2
// baseline (501.988 us; speedup 1.0000x reference)
//
#include <hip/hip_runtime.h>

#define N_PTS   131072
#define NEIGH   32
#define KP      15
#define CIN     64
#define COUT    64
#define M_Q     32768
#define EXTENT  0.24f
#define INV_EXTENT (1.0f/0.24f)
#define EPS     1e-5f
#define NEG_SLOPE 0.01f

#define BM   16     // queries per block
#define QPW  4      // queries per wave (4 waves / block)

__device__ __forceinline__ float readlane_f(float v, int lane) {
  return __uint_as_float((unsigned)__builtin_amdgcn_readlane((int)__float_as_uint(v), lane));
}

__device__ __forceinline__ void fma4(float4& a, float s, const float4& w) {
  a.x = fmaf(s, w.x, a.x); a.y = fmaf(s, w.y, a.y);
  a.z = fmaf(s, w.z, a.z); a.w = fmaf(s, w.w, a.w);
}

__device__ __forceinline__ float4 xor_add4(float4 v, int m) {
  v.x += __shfl_xor(v.x, m); v.y += __shfl_xor(v.y, m);
  v.z += __shfl_xor(v.z, m); v.w += __shfl_xor(v.w, m);
  return v;
}

// ---------------------------------------------------------------------------
// Kernel 1: KPConv features -> feats[M, COUT] (pre-BN), fused BN-stat reduce
// ---------------------------------------------------------------------------
__global__ __launch_bounds__(256, 2)
void kpconv_feats(const float* __restrict__ x,
                  const int*   __restrict__ idx_nb,
                  const float* __restrict__ pos_nb,
                  const int*   __restrict__ idx_s,
                  const float* __restrict__ kpts,
                  const float* __restrict__ kw,
                  float* __restrict__ feats,
                  float* __restrict__ accum)
{
  __shared__ float kp_s[KP*3];                 // kernel points (180 B)
  __shared__ float wf_s[BM][KP*CIN];           // weighted feats: 16*960*4 = 60 KiB
  __shared__ float wt_s[CIN*COUT];             // W_k tile [c][o], XOR-swizzled, 16 KiB
                                               // total ~76.5 KiB -> 2 blocks/CU

  const int tid  = threadIdx.x;
  const int lane = tid & 63;
  const int wv   = tid >> 6;                   // wave 0..3
  const int m0   = blockIdx.x * BM;

  if (tid < KP*3) kp_s[tid] = kpts[tid];
  __syncthreads();

  // ---------------- Phase 1: neighbor weighting + scatter into wf ----------
  for (int qq = 0; qq < QPW; ++qq) {
    const int q = wv*QPW + qq;                 // 0..15 within block
    const int m = m0 + q;
    const int s = idx_s[m];

    // lanes 0..31: one neighbor each
    float w_n  = 0.f;
    int   k_n  = 0;
    int   id_n = N_PTS;
    if (lane < NEIGH) {
      const int base = s*NEIGH + lane;
      id_n = idx_nb[base];
      const float px = pos_nb[base*3+0];
      const float py = pos_nb[base*3+1];
      const float pz = pos_nb[base*3+2];
      float dmin = 3.4e38f;
      int   kmin = 0;
      #pragma unroll
      for (int k = 0; k < KP; ++k) {
        const float dx = px - kp_s[k*3+0];
        const float dy = py - kp_s[k*3+1];
        const float dz = pz - kp_s[k*3+2];
        const float d  = fmaf(dx, dx, fmaf(dy, dy, dz*dz));
        if (d < dmin) { dmin = d; kmin = k; }   // strict < : first-min == argmin
      }
      w_n = fmaxf(0.f, 1.f - sqrtf(dmin)*INV_EXTENT);
      k_n = kmin;
    }

    // lane == channel c; wf[k] accumulators in registers
    float wf[KP];
    #pragma unroll
    for (int k = 0; k < KP; ++k) wf[k] = 0.f;

    #pragma unroll
    for (int half = 0; half < 2; ++half) {
      float xv[16]; float wl[16]; int kl[16];
      // issue all 16 gathers first (independent loads -> deep pipeline)
      #pragma unroll
      for (int j = 0; j < 16; ++j) {
        const int n   = half*16 + j;
        const float wn = readlane_f(w_n, n);                 // SGPR (uniform)
        const int  idn = __builtin_amdgcn_readlane(id_n, n); // SGPR
        kl[j] = __builtin_amdgcn_readlane(k_n, n);           // SGPR
        wl[j] = (idn == N_PTS) ? 0.f : wn;   // shadow point => zero contribution
        const int idc = (idn == N_PTS) ? 0 : idn;
        xv[j] = x[idc*CIN + lane];           // 256B coalesced wave gather
      }
      // wave-uniform scatter (scalar-branch switch; no runtime reg indexing)
      #pragma unroll
      for (int j = 0; j < 16; ++j) {
        #define ACC_CASE(KK) case KK: wf[KK] = fmaf(wl[j], xv[j], wf[KK]); break;
        switch (kl[j]) {
          ACC_CASE(0)  ACC_CASE(1)  ACC_CASE(2)  ACC_CASE(3)  ACC_CASE(4)
          ACC_CASE(5)  ACC_CASE(6)  ACC_CASE(7)  ACC_CASE(8)  ACC_CASE(9)
          ACC_CASE(10) ACC_CASE(11) ACC_CASE(12) ACC_CASE(13) ACC_CASE(14)
        }
        #undef ACC_CASE
      }
    }

    #pragma unroll
    for (int k = 0; k < KP; ++k)
      wf_s[q][k*CIN + lane] = wf[k];          // stride-1, conflict-free
  }

  // ---------------- Phase 2: out[m][o] = sum_{k,c} wf[m][k][c] * W[k][c][o]
  // lane l: owns o-columns 4*(l&15)..+3, c-phase block 16*(l>>4)..+15.
  // Partial sums over c-phases -> shfl_xor(16/32) reduce at the end.
  float4 acc[QPW];
  #pragma unroll
  for (int qq = 0; qq < QPW; ++qq) acc[qq] = make_float4(0.f,0.f,0.f,0.f);

  const int og   = lane & 15;                  // o-group (16B unit within row)
  const int coff = lane >> 4;                  // c-phase 0..3

  for (int k = 0; k < KP; ++k) {
    __syncthreads();   // previous wt_s fully consumed (and at k=0: wf_s visible... own-wave only, but needed for staging order)
    // stage W_k [c][o] straight copy, XOR-swizzle 16B-groups: phys_g = g ^ (c&7)
    {
      const float4* src = reinterpret_cast<const float4*>(kw) + k*(CIN*COUT/4);
      #pragma unroll
      for (int i = 0; i < 4; ++i) {
        const int e4 = i*256 + tid;            // f4 index 0..1023
        const int c  = e4 >> 4;
        const int g  = e4 & 15;
        *reinterpret_cast<float4*>(&wt_s[c*64 + ((g ^ (c & 7)) << 2)]) = src[e4];
      }
    }
    __syncthreads();

    #pragma unroll
    for (int g = 0; g < 4; ++g) {
      float4 w4[4];
      #pragma unroll
      for (int j = 0; j < 4; ++j) {
        const int c = coff*16 + g*4 + j;
        w4[j] = *reinterpret_cast<const float4*>(&wt_s[c*64 + ((og ^ (c & 7)) << 2)]);
      }
      #pragma unroll
      for (int qq = 0; qq < QPW; ++qq) {
        const float4 f4 = *reinterpret_cast<const float4*>(&wf_s[wv*QPW+qq][k*CIN + coff*16 + g*4]);
        fma4(acc[qq], f4.x, w4[0]);
        fma4(acc[qq], f4.y, w4[1]);
        fma4(acc[qq], f4.z, w4[2]);
        fma4(acc[qq], f4.w, w4[3]);
      }
    }
  }

  // cross-lane c-phase reduction: lanes l, l^16, l^32, l^48 hold partials
  #pragma unroll
  for (int qq = 0; qq < QPW; ++qq) {
    acc[qq] = xor_add4(acc[qq], 16);
    acc[qq] = xor_add4(acc[qq], 32);
  }

  // store: lane l writes query wv*4 + (l>>4), o-range 4*(l&15) -> 1KB/wave coalesced
  *reinterpret_cast<float4*>(&feats[(m0 + wv*QPW + coff)*COUT + og*4]) = acc[coff];

  // ---------------- Fused BN-stat partial reduce -------------------------
  float4 psum = make_float4(0.f,0.f,0.f,0.f), psq = psum;
  #pragma unroll
  for (int qq = 0; qq < QPW; ++qq) {
    psum.x += acc[qq].x; psum.y += acc[qq].y; psum.z += acc[qq].z; psum.w += acc[qq].w;
    psq.x = fmaf(acc[qq].x, acc[qq].x, psq.x);
    psq.y = fmaf(acc[qq].y, acc[qq].y, psq.y);
    psq.z = fmaf(acc[qq].z, acc[qq].z, psq.z);
    psq.w = fmaf(acc[qq].w, acc[qq].w, psq.w);
  }
  __syncthreads();               // all waves done reading wt_s -> reuse as scratch
  float* red = wt_s;             // [wv][quad 0..15][comp 0..7]
  if (lane < 16) {
    float4* r = reinterpret_cast<float4*>(&red[wv*128 + lane*8]);
    r[0] = psum;                 // comps 0..3: sum of this wave's 4 queries
    r[1] = psq;                  // comps 4..7: sumsq
  }
  __syncthreads();
  if (tid < 128) {               // tid = quad*8 + comp
    const float v = red[tid] + red[128+tid] + red[256+tid] + red[384+tid];
    const int ch = ((tid >> 3) << 2) | (tid & 3);
    atomicAdd(accum + ((tid & 4) ? 64 : 0) + ch, v);
  }
}

// ---------------------------------------------------------------------------
// Kernel 2: BatchNorm (batch stats) + LeakyReLU, in place on d_out
// ---------------------------------------------------------------------------
__global__ __launch_bounds__(256)
void bn_apply(const float* __restrict__ accum,
              const float* __restrict__ gamma,
              const float* __restrict__ beta,
              float* __restrict__ io)
{
  const int gid = blockIdx.x*256 + threadIdx.x;   // 65536 threads
  const int c4  = (gid*4) & 63;                   // channel base of this thread's float4s
  const float inv_m = 1.0f / (float)M_Q;

  const float4 sum4 = *reinterpret_cast<const float4*>(accum + c4);
  const float4 sq4  = *reinterpret_cast<const float4*>(accum + 64 + c4);
  const float4 g4   = *reinterpret_cast<const float4*>(gamma + c4);
  const float4 b4   = *reinterpret_cast<const float4*>(beta  + c4);

  float sc[4], sh[4];
  {
    const float su[4] = {sum4.x, sum4.y, sum4.z, sum4.w};
    const float qu[4] = {sq4.x,  sq4.y,  sq4.z,  sq4.w};
    const float gg[4] = {g4.x,   g4.y,   g4.z,   g4.w};
    const float bb[4] = {b4.x,   b4.y,   b4.z,   b4.w};
    #pragma unroll
    for (int j = 0; j < 4; ++j) {
      const float mean = su[j] * inv_m;
      const float var  = fmaf(-mean, mean, qu[j] * inv_m);  // biased var (ddof=0)
      sc[j] = gg[j] * rsqrtf(var + EPS);
      sh[j] = fmaf(-mean, sc[j], bb[j]);
    }
  }

  float4* p = reinterpret_cast<float4*>(io);
  for (int i = gid; i < (M_Q*COUT)/4; i += 65536) {
    float4 v = p[i];
    float e[4] = {v.x, v.y, v.z, v.w};
    #pragma unroll
    for (int j = 0; j < 4; ++j) {
      const float y = fmaf(e[j], sc[j], sh[j]);
      e[j] = (y >= 0.f) ? y : NEG_SLOPE * y;
    }
    v.x = e[0]; v.y = e[1]; v.z = e[2]; v.w = e[3];
    p[i] = v;
  }
}

// ---------------------------------------------------------------------------
extern "C" void kernel_launch(void* const* d_in, const int* in_sizes, int n_in,
                              void* d_out, int out_size, void* d_ws, size_t ws_size,
                              hipStream_t stream)
{
  const float* x     = (const float*)d_in[0];
  const int*   idxn  = (const int*)  d_in[1];
  const float* posn  = (const float*)d_in[2];
  const int*   idxs  = (const int*)  d_in[3];
  const float* kpts  = (const float*)d_in[4];
  const float* kw    = (const float*)d_in[5];
  const float* gamma = (const float*)d_in[6];
  const float* beta  = (const float*)d_in[7];
  float* out   = (float*)d_out;
  float* accum = (float*)d_ws;     // 128 floats: [0..63]=sum, [64..127]=sumsq

  hipMemsetAsync(accum, 0, 128*sizeof(float), stream);
  kpconv_feats<<<M_Q/BM, 256, 0, stream>>>(x, idxn, posn, idxs, kpts, kw, out, accum);
  bn_apply<<<256, 256, 0, stream>>>(accum, gamma, beta, out);
}

// Round 8
// 236.175 us; speedup vs baseline: 2.1255x; 2.1255x over previous
//
#include <hip/hip_runtime.h>

#define N_PTS   131072
#define NEIGH   32
#define KP      15
#define CIN     64
#define COUT    64
#define M_Q     32768
#define EXTENT  0.24f
#define INV_EXTENT (1.0f/0.24f)
#define EPS     1e-5f
#define NEG_SLOPE 0.01f

#define BM   16      // queries per block
#define QPW  4       // queries per wave (4 waves / block)
#define KSTEPS 30    // 960 / 32
#define PITCH 968    // ushort pitch per query row: 1936B = 121*16 -> b128-aligned, bank-balanced
#define WSLOTS 7680  // 4 ntiles * 30 ksteps * 64 lanes (per hi/lo part)

typedef short s8v __attribute__((ext_vector_type(8)));
typedef float f4v __attribute__((ext_vector_type(4)));

__device__ __forceinline__ float readlane_f(float v, int lane) {
  return __uint_as_float((unsigned)__builtin_amdgcn_readlane((int)__float_as_uint(v), lane));
}
__device__ __forceinline__ unsigned short f2bf(float f) {   // RNE fp32 -> bf16
  unsigned u = __float_as_uint(f);
  u = u + 0x7FFFu + ((u >> 16) & 1u);
  return (unsigned short)(u >> 16);
}
__device__ __forceinline__ float bf2f(unsigned short h) {
  return __uint_as_float(((unsigned)h) << 16);
}

// ---------------------------------------------------------------------------
// Kernel 0: split W into hi/lo bf16 MFMA-B fragments in ws.
// slot t = wv*1920 + kstep*64 + lane ; elem j: B[k0+j][o], k0=kstep*32+(lane>>4)*8,
// o = wv*16 + (lane&15).  hi at slot t, lo at slot WSLOTS+t (16B each).
// ---------------------------------------------------------------------------
__global__ __launch_bounds__(256)
void wsplit_prep(const float* __restrict__ kw, unsigned short* __restrict__ wsW)
{
  const int t = blockIdx.x*256 + threadIdx.x;
  if (t >= WSLOTS) return;
  const int wv    = t / 1920;
  const int r1    = t - wv*1920;
  const int kstep = r1 >> 6;
  const int lane  = r1 & 63;
  const int k0 = kstep*32 + ((lane>>4)<<3);
  const int o  = wv*16 + (lane&15);
  s8v hv, lv;
  #pragma unroll
  for (int j = 0; j < 8; ++j) {
    const float v = kw[(k0+j)*COUT + o];
    const unsigned short h = f2bf(v);
    hv[j] = (short)h;
    lv[j] = (short)f2bf(v - bf2f(h));
  }
  reinterpret_cast<s8v*>(wsW)[t]          = hv;
  reinterpret_cast<s8v*>(wsW)[WSLOTS + t] = lv;
}

// ---------------------------------------------------------------------------
// Kernel 1: KPConv features -> feats[M, COUT] (pre-BN) + fused BN-stat reduce
// ---------------------------------------------------------------------------
__global__ __launch_bounds__(256, 2)
void kpconv_feats(const float* __restrict__ x,
                  const int*   __restrict__ idx_nb,
                  const float* __restrict__ pos_nb,
                  const int*   __restrict__ idx_s,
                  const float* __restrict__ kpts,
                  const unsigned short* __restrict__ wsW,
                  float* __restrict__ feats,
                  float* __restrict__ accum)
{
  __shared__ float kp_s[KP*3];
  __shared__ __align__(16) unsigned short hi_s[BM*PITCH];  // wf hi-plane, 30.25 KiB
  __shared__ __align__(16) unsigned short lo_s[BM*PITCH];  // wf lo-plane, 30.25 KiB

  const int tid  = threadIdx.x;
  const int lane = tid & 63;
  const int wv   = tid >> 6;
  const int m0   = blockIdx.x * BM;

  if (tid < KP*3) kp_s[tid] = kpts[tid];
  __syncthreads();

  // ---- Phase 1a: metadata for this wave's 4 queries, 2 at a time (full wave)
  const int q2 = lane >> 5;
  const int nn = lane & 31;
  float w_m[2]; int id_m[2], k_m[2];
  #pragma unroll
  for (int r = 0; r < 2; ++r) {
    const int m    = m0 + wv*QPW + r*2 + q2;
    const int s    = idx_s[m];
    const int base = s*NEIGH + nn;
    const int idv  = idx_nb[base];
    const float px = pos_nb[base*3+0];
    const float py = pos_nb[base*3+1];
    const float pz = pos_nb[base*3+2];
    float dmin = 3.4e38f; int kmin = 0;
    #pragma unroll
    for (int k = 0; k < KP; ++k) {
      const float dx = px - kp_s[k*3+0];
      const float dy = py - kp_s[k*3+1];
      const float dz = pz - kp_s[k*3+2];
      const float d  = fmaf(dx, dx, fmaf(dy, dy, dz*dz));
      if (d < dmin) { dmin = d; kmin = k; }    // strict < : first-min == argmin
    }
    const float wnb = fmaxf(0.f, 1.f - sqrtf(dmin)*INV_EXTENT);
    w_m[r]  = (idv == N_PTS) ? 0.f : wnb;      // shadow point -> zero weight
    id_m[r] = (idv == N_PTS) ? 0   : idv;      // safe gather index
    k_m[r]  = kmin;
  }

  // ---- Phase 1b: pipelined gathers + branchless select-FMA scatter --------
  float wf[KP];
  #pragma unroll
  for (int k = 0; k < KP; ++k) wf[k] = 0.f;
  float xv0[16], xv1[16];

  // batch B (0..7): query q=B>>1, half h=B&1; metadata owner lane = (q&1)*32+h*16+j
  #define ISSUE(B, XV) do {                                                   \
    constexpr int q_ = (B)>>1;                                                \
    constexpr int sb_ = (q_&1)*32 + ((B)&1)*16;                               \
    constexpr int r_ = q_>>1;                                                 \
    _Pragma("unroll")                                                         \
    for (int j = 0; j < 16; ++j) {                                            \
      const int sid = __builtin_amdgcn_readlane(id_m[r_], sb_+j);             \
      XV[j] = x[sid*CIN + lane];                                              \
    } } while(0)

  #define CONSUME(B, XV) do {                                                 \
    constexpr int q_ = (B)>>1;                                                \
    constexpr int sb_ = (q_&1)*32 + ((B)&1)*16;                               \
    constexpr int r_ = q_>>1;                                                 \
    _Pragma("unroll")                                                         \
    for (int j = 0; j < 16; ++j) {                                            \
      const float wl = readlane_f(w_m[r_], sb_+j);                            \
      const int   kl = __builtin_amdgcn_readlane(k_m[r_], sb_+j);             \
      const float xj = XV[j];                                                 \
      _Pragma("unroll")                                                       \
      for (int k = 0; k < KP; ++k)                                            \
        wf[k] = fmaf((kl == k) ? wl : 0.0f, xj, wf[k]);                       \
    } } while(0)

  // store query Q's wf as bf16 hi/lo planes (split done once per element)
  #define STOREQ(Q) do {                                                      \
    const int rowb_ = (wv*QPW + (Q))*PITCH;                                   \
    _Pragma("unroll")                                                         \
    for (int k = 0; k < KP; ++k) {                                            \
      const unsigned short h_ = f2bf(wf[k]);                                  \
      hi_s[rowb_ + k*CIN + lane] = h_;                                        \
      lo_s[rowb_ + k*CIN + lane] = f2bf(wf[k] - bf2f(h_));                    \
      wf[k] = 0.f;                                                            \
    } } while(0)

  ISSUE(0, xv0);
  ISSUE(1, xv1); CONSUME(0, xv0);
  ISSUE(2, xv0); CONSUME(1, xv1); STOREQ(0);
  ISSUE(3, xv1); CONSUME(2, xv0);
  ISSUE(4, xv0); CONSUME(3, xv1); STOREQ(1);
  ISSUE(5, xv1); CONSUME(4, xv0);
  ISSUE(6, xv0); CONSUME(5, xv1); STOREQ(2);
  ISSUE(7, xv1); CONSUME(6, xv0);
                 CONSUME(7, xv1); STOREQ(3);
  #undef ISSUE
  #undef CONSUME
  #undef STOREQ

  __syncthreads();   // all 16 wf rows visible to all waves

  // ---- Phase 2: MFMA GEMM  D[16q x 16o] per wave (wave wv = o-tile wv)
  // A[row][k]: row = lane&15 (query), k = kstep*32 + (lane>>4)*8 + j
  // B[k][col]: col = lane&15 (o within tile), same k slices -> precomputed wsW
  // 3-term bf16 split: Ah*Bh + Ah*Bl + Al*Bh.  FULLY unrolled so the
  // scheduler can hoist the 120 global B-loads well ahead of their MFMAs
  // (2 waves/SIMD only -> ILP must cover the ~200cy L2 latency).
  const int row = lane & 15;
  const int kg  = lane >> 4;
  const s8v* Bh = reinterpret_cast<const s8v*>(wsW) + wv*(KSTEPS*64) + lane;
  const s8v* Bl = Bh + WSLOTS;

  f4v a0 = {0.f,0.f,0.f,0.f}, a1 = a0, a2 = a0;
  const int abase = row*PITCH + kg*8;

  #pragma unroll
  for (int ks = 0; ks < KSTEPS; ++ks) {
    const s8v ah = *reinterpret_cast<const s8v*>(&hi_s[abase + ks*32]);
    const s8v al = *reinterpret_cast<const s8v*>(&lo_s[abase + ks*32]);
    const s8v bh = Bh[ks*64];
    const s8v bl = Bl[ks*64];
    a0 = __builtin_amdgcn_mfma_f32_16x16x32_bf16(ah, bh, a0, 0, 0, 0);
    a1 = __builtin_amdgcn_mfma_f32_16x16x32_bf16(ah, bl, a1, 0, 0, 0);
    a2 = __builtin_amdgcn_mfma_f32_16x16x32_bf16(al, bh, a2, 0, 0, 0);
  }
  f4v acc = a0 + a1 + a2;

  // C/D layout: col = lane&15 -> o = wv*16 + col; query row = kg*4 + reg
  const int o = wv*16 + row;
  #pragma unroll
  for (int r = 0; r < 4; ++r)
    feats[(m0 + (kg*4 + r))*COUT + o] = acc[r];

  // ---- fused BN-stat partial reduce (register-only, no extra barrier) -----
  float s  = acc[0] + acc[1] + acc[2] + acc[3];
  float sq = fmaf(acc[0],acc[0], fmaf(acc[1],acc[1],
             fmaf(acc[2],acc[2], acc[3]*acc[3])));
  s  += __shfl_xor(s, 16);  s  += __shfl_xor(s, 32);   // combine the 4 row-groups
  sq += __shfl_xor(sq, 16); sq += __shfl_xor(sq, 32);  // (same o across them)
  if (lane < 16) {
    atomicAdd(accum + o,      s);
    atomicAdd(accum + 64 + o, sq);
  }
}

// ---------------------------------------------------------------------------
// Kernel 2: BatchNorm (batch stats) + LeakyReLU, in place on d_out
// ---------------------------------------------------------------------------
__global__ __launch_bounds__(256)
void bn_apply(const float* __restrict__ accum,
              const float* __restrict__ gamma,
              const float* __restrict__ beta,
              float* __restrict__ io)
{
  const int gid = blockIdx.x*256 + threadIdx.x;   // 65536 threads
  const int c4  = (gid*4) & 63;
  const float inv_m = 1.0f / (float)M_Q;

  const float4 sum4 = *reinterpret_cast<const float4*>(accum + c4);
  const float4 sq4  = *reinterpret_cast<const float4*>(accum + 64 + c4);
  const float4 g4   = *reinterpret_cast<const float4*>(gamma + c4);
  const float4 b4   = *reinterpret_cast<const float4*>(beta  + c4);

  float sc[4], sh[4];
  {
    const float su[4] = {sum4.x, sum4.y, sum4.z, sum4.w};
    const float qu[4] = {sq4.x,  sq4.y,  sq4.z,  sq4.w};
    const float gg[4] = {g4.x,   g4.y,   g4.z,   g4.w};
    const float bb[4] = {b4.x,   b4.y,   b4.z,   b4.w};
    #pragma unroll
    for (int j = 0; j < 4; ++j) {
      const float mean = su[j] * inv_m;
      const float var  = fmaf(-mean, mean, qu[j] * inv_m);  // biased var (ddof=0)
      sc[j] = gg[j] * rsqrtf(var + EPS);
      sh[j] = fmaf(-mean, sc[j], bb[j]);
    }
  }

  float4* p = reinterpret_cast<float4*>(io);
  for (int i = gid; i < (M_Q*COUT)/4; i += 65536) {
    float4 v = p[i];
    float e[4] = {v.x, v.y, v.z, v.w};
    #pragma unroll
    for (int j = 0; j < 4; ++j) {
      const float y = fmaf(e[j], sc[j], sh[j]);
      e[j] = (y >= 0.f) ? y : NEG_SLOPE * y;
    }
    v.x = e[0]; v.y = e[1]; v.z = e[2]; v.w = e[3];
    p[i] = v;
  }
}

// ---------------------------------------------------------------------------
extern "C" void kernel_launch(void* const* d_in, const int* in_sizes, int n_in,
                              void* d_out, int out_size, void* d_ws, size_t ws_size,
                              hipStream_t stream)
{
  const float* x     = (const float*)d_in[0];
  const int*   idxn  = (const int*)  d_in[1];
  const float* posn  = (const float*)d_in[2];
  const int*   idxs  = (const int*)  d_in[3];
  const float* kpts  = (const float*)d_in[4];
  const float* kw    = (const float*)d_in[5];
  const float* gamma = (const float*)d_in[6];
  const float* beta  = (const float*)d_in[7];
  float* out   = (float*)d_out;
  float* accum = (float*)d_ws;                                   // 128 f32
  unsigned short* wsW = (unsigned short*)((char*)d_ws + 512);    // 2*7680 slots * 16B

  hipMemsetAsync(accum, 0, 128*sizeof(float), stream);
  wsplit_prep<<<(WSLOTS + 255)/256, 256, 0, stream>>>(kw, wsW);
  kpconv_feats<<<M_Q/BM, 256, 0, stream>>>(x, idxn, posn, idxs, kpts, wsW, out, accum);
  bn_apply<<<256, 256, 0, stream>>>(accum, gamma, beta, out);
}